// Round 10
// baseline (1125.772 us; speedup 1.0000x reference)
//
#include <hip/hip_runtime.h>
#include <math.h>

#define N_NODES 100000
#define N_EDGES 400000
#define N_GRAPH 4096
#define DIM 128
#define HEADS 8
#define CHD 16
#define LAYERS 4
#define EPS_BN 1e-5f
#define BN_BLK 256

// bf16 helpers (RN-even pack, cheap unpack)
static __device__ __forceinline__ unsigned short f2bf(float f) {
  unsigned int u = __float_as_uint(f);
  u += 0x7FFFu + ((u >> 16) & 1u);
  return (unsigned short)(u >> 16);
}
static __device__ __forceinline__ float bf2f(unsigned short h) {
  return __uint_as_float(((unsigned int)h) << 16);
}

// ---------------------------------------------------------------------------
// K1: fold W_eproj/att_edge/W_edge/b_edge into small3[L][3][8] + biasE[L][8]
// ---------------------------------------------------------------------------
__global__ void k_prep(const float* __restrict__ W_eproj, const float* __restrict__ att_edge,
                       const float* __restrict__ W_edge, const float* __restrict__ b_edge,
                       float* __restrict__ small3, float* __restrict__ biasE) {
  __shared__ float sw[DIM * 32];   // w_e_att[d][l*8+h]
  int t = threadIdx.x;
  for (int e = t; e < DIM * 32; e += 256) {
    int d = e >> 5, lh = e & 31, l = lh >> 3, hh = lh & 7;
    float s = 0.f;
    const float* wp = W_eproj + ((size_t)l * DIM + d) * DIM + hh * CHD;
    const float* ap = att_edge + (l * HEADS + hh) * CHD;
    #pragma unroll
    for (int c = 0; c < CHD; ++c) s += wp[c] * ap[c];
    sw[e] = s;
  }
  __syncthreads();
  if (t < 96) {                       // small3[l][k][h]
    int l = t / 24, r = t % 24, k = r / 8, hh = r % 8;
    float s = 0.f;
    for (int d = 0; d < DIM; ++d) s += W_edge[k * DIM + d] * sw[d * 32 + l * 8 + hh];
    small3[t] = s;
  } else if (t < 128) {               // biasE[l][h]
    int t2 = t - 96, l = t2 / 8, hh = t2 % 8;
    float s = 0.f;
    for (int d = 0; d < DIM; ++d) s += b_edge[d] * sw[d * 32 + l * 8 + hh];
    biasE[t2] = s;
  }
}

// ---------------------------------------------------------------------------
// K2: node encoder hEnc = x @ W_node + b_node (hEnc doubles as residual)
// ---------------------------------------------------------------------------
__global__ void k_encode(const float* __restrict__ x, const float* __restrict__ Wn,
                         const float* __restrict__ bn, float* __restrict__ hEnc) {
  __shared__ float sw[9 * DIM];
  __shared__ float sb[DIM];
  int t = threadIdx.x;
  for (int i = t; i < 9 * DIM; i += 256) sw[i] = Wn[i];
  if (t < DIM) sb[t] = bn[t];
  __syncthreads();
  size_t id = (size_t)blockIdx.x * 256 + t;
  if (id >= (size_t)N_NODES * DIM) return;
  int n = (int)(id >> 7), d = (int)(id & 127);
  float s = sb[d];
  const float* xr = x + (size_t)n * 9;
  #pragma unroll
  for (int k = 0; k < 9; ++k) s += xr[k] * sw[k * DIM + d];
  hEnc[id] = s;
}

// ---------------------------------------------------------------------------
// K3: in-degree histogram (int atomics only)
// ---------------------------------------------------------------------------
__global__ void k_deg(const int* __restrict__ dst, int* __restrict__ deg) {
  int i = blockIdx.x * 256 + threadIdx.x;
  if (i >= N_EDGES) return;
  atomicAdd(&deg[dst[i]], 1);
}

// ---------------------------------------------------------------------------
// K4: 3-kernel exclusive scan of deg -> row_ptr
// ---------------------------------------------------------------------------
__global__ void k_scan1(const int* __restrict__ deg, int* __restrict__ rp, int* __restrict__ bsum) {
  __shared__ int s[256];
  int t = threadIdx.x, i = blockIdx.x * 256 + t;
  int v = (i < N_NODES) ? deg[i] : 0;
  s[t] = v;
  __syncthreads();
  for (int off = 1; off < 256; off <<= 1) {
    int u = (t >= off) ? s[t - off] : 0;
    __syncthreads();
    s[t] += u;
    __syncthreads();
  }
  if (i < N_NODES) rp[i] = s[t] - v;
  if (t == 255) bsum[blockIdx.x] = s[255];
}

__global__ void k_scan2(int* __restrict__ bsum, int nb) {
  __shared__ int s[512];
  int t = threadIdx.x;
  int v = (t < nb) ? bsum[t] : 0;
  s[t] = v;
  __syncthreads();
  for (int off = 1; off < 512; off <<= 1) {
    int u = (t >= off) ? s[t - off] : 0;
    __syncthreads();
    s[t] += u;
    __syncthreads();
  }
  if (t < nb) bsum[t] = s[t] - v;
}

__global__ void k_scan3(int* __restrict__ rp, const int* __restrict__ bsum) {
  int i = blockIdx.x * 256 + threadIdx.x;
  if (i < N_NODES) rp[i] += bsum[blockIdx.x];
  if (blockIdx.x == 0 && threadIdx.x == 0) rp[N_NODES] = N_EDGES;
}

// ---------------------------------------------------------------------------
// K5: CSR scatter — stores (src,dst) pair and the edge_attr row at the slot
// ---------------------------------------------------------------------------
__global__ void k_scatter(const int* __restrict__ src, const int* __restrict__ dst,
                          const float* __restrict__ ea, const int* __restrict__ rp,
                          int* __restrict__ fill, int2* __restrict__ cpair,
                          float* __restrict__ cea) {
  int i = blockIdx.x * 256 + threadIdx.x;
  if (i >= N_EDGES) return;
  int d = dst[i];
  int p = rp[d] + atomicAdd(&fill[d], 1);
  cpair[p] = make_int2(src[i], d);
  cea[(size_t)p * 3 + 0] = ea[(size_t)i * 3 + 0];
  cea[(size_t)p * 3 + 1] = ea[(size_t)i * 3 + 1];
  cea[(size_t)p * 3 + 2] = ea[(size_t)i * 3 + 2];
}

// ---------------------------------------------------------------------------
// K5b: easum[n] = contiguous sum of cea over the node's CSR range
// ---------------------------------------------------------------------------
__global__ void k_easum(const int* __restrict__ rp, const float* __restrict__ cea,
                        float* __restrict__ easum) {
  int n = blockIdx.x * 256 + threadIdx.x;
  if (n >= N_NODES) return;
  int p0 = rp[n], p1 = rp[n + 1];
  float s0 = 0.f, s1 = 0.f, s2 = 0.f;
  for (int p = p0; p < p1; ++p) {
    s0 += cea[(size_t)p * 3 + 0];
    s1 += cea[(size_t)p * 3 + 1];
    s2 += cea[(size_t)p * 3 + 2];
  }
  easum[n * 3 + 0] = s0;
  easum[n * 3 + 1] = s1;
  easum[n * 3 + 2] = s2;
}

// ---------------------------------------------------------------------------
// K6: hp = f(h) @ W_lin[l], 128x128 tile, acc[8][8]/thread, conflict-free LDS.
// hp is stored BF16 (messages only; a_s/a_d stay fp32 from fp32 accumulators).
// mode 0: raw rows; 1: relu(v*g+b); 2: relu(v*g+b)+hEnc (residual).
// ---------------------------------------------------------------------------
__launch_bounds__(256)
__global__ void k_gemm_hp(const float* __restrict__ hsrc, const float* __restrict__ hEnc,
                          const float* __restrict__ ssv, int mode,
                          const float* __restrict__ W,
                          const float* __restrict__ attS, const float* __restrict__ attD,
                          unsigned short* __restrict__ hp, float* __restrict__ a_s,
                          float* __restrict__ a_d) {
  __shared__ float sW[32 * DIM];    // 16 KB: W chunk, 32 k-rows x 128 cols
  __shared__ float sH[128 * 32];    // 16 KB: H chunk, swizzled float4 slots
  int t = threadIdx.x;
  int row0 = blockIdx.x * 128;
  int tx = t & 15, ty = t >> 4;
  int r0 = ty * 8;                  // 8 output rows per thread
  int cA = tx * 4;                  // first output col quad
  int cB = 64 + tx * 4;             // second output col quad
  int swz = ty & 7;
  float acc[8][8] = {};
  for (int kk = 0; kk < DIM; kk += 32) {
    #pragma unroll
    for (int i = 0; i < 4; ++i) {   // W chunk: contiguous per row
      int e = t + i * 256;
      int row = e >> 5, col4 = (e & 31) << 2;
      *reinterpret_cast<float4*>(&sW[row * DIM + col4]) =
          *reinterpret_cast<const float4*>(W + (size_t)(kk + row) * DIM + col4);
    }
    #pragma unroll
    for (int i = 0; i < 4; ++i) {   // H chunk (+BN), swizzled placement
      int e = t + i * 256;
      int rr = e >> 3, c4 = e & 7;
      int grr = row0 + rr;
      int col = kk + c4 * 4;
      float4 v = make_float4(0.f, 0.f, 0.f, 0.f);
      if (grr < N_NODES) {
        v = *reinterpret_cast<const float4*>(hsrc + (size_t)grr * DIM + col);
        if (mode >= 1) {
          float4 g = *reinterpret_cast<const float4*>(ssv + col);
          float4 b = *reinterpret_cast<const float4*>(ssv + DIM + col);
          v.x = fmaxf(v.x * g.x + b.x, 0.f);
          v.y = fmaxf(v.y * g.y + b.y, 0.f);
          v.z = fmaxf(v.z * g.z + b.z, 0.f);
          v.w = fmaxf(v.w * g.w + b.w, 0.f);
          if (mode == 2) {
            float4 r4 = *reinterpret_cast<const float4*>(hEnc + (size_t)grr * DIM + col);
            v.x += r4.x; v.y += r4.y; v.z += r4.z; v.w += r4.w;
          }
        }
      }
      int slot = c4 ^ ((rr >> 3) & 7);
      *reinterpret_cast<float4*>(&sH[rr * 32 + slot * 4]) = v;
    }
    __syncthreads();
    for (int k = 0; k < 32; k += 4) {
      int c4s = (k >> 2) ^ swz;
      float4 a[8];
      #pragma unroll
      for (int r = 0; r < 8; ++r)
        a[r] = *reinterpret_cast<const float4*>(&sH[(r0 + r) * 32 + c4s * 4]);
      #pragma unroll
      for (int k2 = 0; k2 < 4; ++k2) {
        float4 wA = *reinterpret_cast<const float4*>(&sW[(k + k2) * DIM + cA]);
        float4 wB = *reinterpret_cast<const float4*>(&sW[(k + k2) * DIM + cB]);
        #pragma unroll
        for (int r = 0; r < 8; ++r) {
          float av = (k2 == 0) ? a[r].x : (k2 == 1) ? a[r].y : (k2 == 2) ? a[r].z : a[r].w;
          acc[r][0] += av * wA.x; acc[r][1] += av * wA.y;
          acc[r][2] += av * wA.z; acc[r][3] += av * wA.w;
          acc[r][4] += av * wB.x; acc[r][5] += av * wB.y;
          acc[r][6] += av * wB.z; acc[r][7] += av * wB.w;
        }
      }
    }
    __syncthreads();
  }
  // epilogue: cols cA..cA+3 = head hA; cB quad = head hA+4; reduce over tx&3
  int hA = tx >> 2;
  int cin0 = (tx & 3) * 4;
  float wsA[4], wdA[4], wsB[4], wdB[4];
  #pragma unroll
  for (int j = 0; j < 4; ++j) {
    wsA[j] = attS[hA * CHD + cin0 + j];
    wdA[j] = attD[hA * CHD + cin0 + j];
    wsB[j] = attS[(hA + 4) * CHD + cin0 + j];
    wdB[j] = attD[(hA + 4) * CHD + cin0 + j];
  }
  #pragma unroll
  for (int r = 0; r < 8; ++r) {
    int n = row0 + r0 + r;
    float psA = 0.f, pdA = 0.f, psB = 0.f, pdB = 0.f;
    #pragma unroll
    for (int j = 0; j < 4; ++j) {
      psA += acc[r][j] * wsA[j];
      pdA += acc[r][j] * wdA[j];
      psB += acc[r][4 + j] * wsB[j];
      pdB += acc[r][4 + j] * wdB[j];
    }
    psA += __shfl_xor(psA, 1); psA += __shfl_xor(psA, 2);
    pdA += __shfl_xor(pdA, 1); pdA += __shfl_xor(pdA, 2);
    psB += __shfl_xor(psB, 1); psB += __shfl_xor(psB, 2);
    pdB += __shfl_xor(pdB, 1); pdB += __shfl_xor(pdB, 2);
    if (n < N_NODES) {
      ushort4 pa = make_ushort4(f2bf(acc[r][0]), f2bf(acc[r][1]),
                                f2bf(acc[r][2]), f2bf(acc[r][3]));
      ushort4 pb = make_ushort4(f2bf(acc[r][4]), f2bf(acc[r][5]),
                                f2bf(acc[r][6]), f2bf(acc[r][7]));
      *reinterpret_cast<ushort4*>(hp + (size_t)n * DIM + cA) = pa;
      *reinterpret_cast<ushort4*>(hp + (size_t)n * DIM + cB) = pb;
      if ((tx & 3) == 0) {
        a_s[(size_t)n * HEADS + hA] = psA;
        a_s[(size_t)n * HEADS + hA + 4] = psB;
        a_d[(size_t)n * HEADS + hA] = pdA;
        a_d[(size_t)n * HEADS + hA + 4] = pdB;
      }
    }
  }
}

// ---------------------------------------------------------------------------
// K7: FUSED alpha + segment-softmax + aggregation. One wave per node.
// hp gathered as BF16 (halved bytes); weights/logits fp32.
// ---------------------------------------------------------------------------
__launch_bounds__(256)
__global__ void k_attagg(const unsigned short* __restrict__ hp, const int* __restrict__ rp,
                         const int2* __restrict__ cpair, const float* __restrict__ cea,
                         const float* __restrict__ a_s, const float* __restrict__ a_d,
                         const float* __restrict__ easum, const float* __restrict__ small3,
                         const float* __restrict__ biasE, const float* __restrict__ gbias,
                         float* __restrict__ out, int l) {
  __shared__ float sc[32];   // small3[l] (24) + biasE[l] (8)
  int t = threadIdx.x;
  if (t < 24) sc[t] = small3[l * 24 + t];
  else if (t < 32) sc[t] = biasE[l * 8 + (t - 24)];
  __syncthreads();
  int wv = t >> 6, lane = t & 63;
  int n = blockIdx.x * 4 + wv;
  if (n >= N_NODES) return;
  int p0 = rp[n], p1 = rp[n + 1];
  int deg = p1 - p0;
  int hh = lane & 7, sub = lane >> 3;
  int h0 = lane >> 4, h1 = h0 + 4;
  float adh = a_d[(size_t)n * 8 + hh];
  float dg = (float)deg, invd = 1.f / fmaxf(dg, 1.f);
  float se0 = easum[n * 3 + 0], se1 = easum[n * 3 + 1], se2 = easum[n * 3 + 2];
  float aeS = (se0 * sc[hh] + se1 * sc[8 + hh] + se2 * sc[16 + hh] + dg * sc[24 + hh]) * invd;
  float lgS = a_s[(size_t)n * 8 + hh] + adh + aeS;
  lgS = (lgS > 0.f) ? lgS : 0.2f * lgS;
  float eS = expf(lgS);
  float s = (sub == 0) ? eS : 0.f;
  float acc0 = 0.f, acc1 = 0.f;
  for (int j0 = 0; j0 < deg; j0 += 8) {
    int idx = j0 + sub;
    float e = 0.f;
    int myc = 0;
    if (idx < deg) {
      int p = p0 + idx;
      myc = cpair[p].x;
      float c0v = cea[(size_t)p * 3 + 0], c1v = cea[(size_t)p * 3 + 1], c2v = cea[(size_t)p * 3 + 2];
      float ae = c0v * sc[hh] + c1v * sc[8 + hh] + c2v * sc[16 + hh] + sc[24 + hh];
      float lg = a_s[(size_t)myc * 8 + hh] + adh + ae;
      lg = (lg > 0.f) ? lg : 0.2f * lg;
      e = expf(lg);
    }
    s += e;
    int kmax = min(8, deg - j0);
    for (int k = 0; k < kmax; ++k) {
      int sa = __shfl(myc, k * 8);          // lane (sub=k, hh=0) holds src
      float w0 = __shfl(e, k * 8 + h0);
      float w1 = __shfl(e, k * 8 + h1);
      acc0 += w0 * bf2f(hp[(size_t)sa * DIM + lane]);
      acc1 += w1 * bf2f(hp[(size_t)sa * DIM + 64 + lane]);
    }
  }
  s += __shfl_xor(s, 8); s += __shfl_xor(s, 16); s += __shfl_xor(s, 32);
  float inv = 1.f / (s + 1e-16f);
  float i0 = __shfl(inv, h0), i1 = __shfl(inv, h1);
  float eS0 = __shfl(eS, h0), eS1 = __shfl(eS, h1);   // lanes 0..7 hold heads 0..7
  acc0 += eS0 * bf2f(hp[(size_t)n * DIM + lane]);
  acc1 += eS1 * bf2f(hp[(size_t)n * DIM + 64 + lane]);
  out[(size_t)n * DIM + lane] = acc0 * i0 + gbias[lane];
  out[(size_t)n * DIM + 64 + lane] = acc1 * i1 + gbias[64 + lane];
}

// ---------------------------------------------------------------------------
// K9: BN stats -> per-block partials (no atomics). K10: reduce + scale/shift.
// ---------------------------------------------------------------------------
__launch_bounds__(256)
__global__ void k_bnstat(const float* __restrict__ h, double* __restrict__ partial) {
  int t = threadIdx.x;
  int c = t & 127, half = t >> 7;
  double s = 0.0, q = 0.0;
  for (int n = blockIdx.x * 2 + half; n < N_NODES; n += BN_BLK * 2) {
    float v = h[(size_t)n * DIM + c];
    s += (double)v;
    q += (double)v * (double)v;
  }
  __shared__ double sd[512];
  sd[t] = s; sd[256 + t] = q;
  __syncthreads();
  if (t < 128) {
    s = sd[t] + sd[t + 128];
    q = sd[256 + t] + sd[256 + t + 128];
    partial[(size_t)blockIdx.x * 256 + t] = s;
    partial[(size_t)blockIdx.x * 256 + 128 + t] = q;
  }
}

__global__ void k_bnfin(const double* __restrict__ partial, const float* __restrict__ gamma,
                        const float* __restrict__ beta, float* __restrict__ ss) {
  int c = threadIdx.x;   // 128
  double s = 0.0, q = 0.0;
  for (int b = 0; b < BN_BLK; ++b) {
    s += partial[(size_t)b * 256 + c];
    q += partial[(size_t)b * 256 + 128 + c];
  }
  double mu = s / (double)N_NODES;
  double var = q / (double)N_NODES - mu * mu;
  if (var < 0.0) var = 0.0;
  float rs = rsqrtf((float)var + EPS_BN);
  float g = gamma[c] * rs;
  ss[c] = g;
  ss[DIM + c] = beta[c] - (float)mu * g;
}

// ---------------------------------------------------------------------------
// K12: gate MLP as register-blocked tile GEMM; layer-3 BN+ReLU fused in staging
// ---------------------------------------------------------------------------
__launch_bounds__(256, 2)
__global__ void k_gate(const float* __restrict__ hAgg, const float* __restrict__ ss,
                       const float* __restrict__ W1, const float* __restrict__ b1,
                       const float* __restrict__ W2, const float* __restrict__ b2,
                       float* __restrict__ gate) {
  __shared__ float sHT[128][64];   // 32 KB: sHT[k][node]
  __shared__ float red[16][64];    // 4 KB
  int t = threadIdx.x;
  int row0 = blockIdx.x * 64;
  {
    int node = t & 63, kq = t >> 6;
    int gn = row0 + node;
    const float* hr = hAgg + (size_t)gn * DIM + kq * 32;
    #pragma unroll
    for (int c = 0; c < 8; ++c) {
      int col = kq * 32 + c * 4;
      float4 v = (gn < N_NODES) ? *reinterpret_cast<const float4*>(hr + c * 4)
                                : make_float4(0.f, 0.f, 0.f, 0.f);
      float4 g = *reinterpret_cast<const float4*>(ss + col);
      float4 b = *reinterpret_cast<const float4*>(ss + DIM + col);
      sHT[col + 0][node] = fmaxf(v.x * g.x + b.x, 0.f);
      sHT[col + 1][node] = fmaxf(v.y * g.y + b.y, 0.f);
      sHT[col + 2][node] = fmaxf(v.z * g.z + b.z, 0.f);
      sHT[col + 3][node] = fmaxf(v.w * g.w + b.w, 0.f);
    }
  }
  __syncthreads();
  int tx = t & 15, ty = t >> 4;
  float acc[4][4] = {};
  for (int k = 0; k < 128; k += 4) {
    float4 a0 = *reinterpret_cast<const float4*>(&sHT[k + 0][tx * 4]);
    float4 a1 = *reinterpret_cast<const float4*>(&sHT[k + 1][tx * 4]);
    float4 a2 = *reinterpret_cast<const float4*>(&sHT[k + 2][tx * 4]);
    float4 a3 = *reinterpret_cast<const float4*>(&sHT[k + 3][tx * 4]);
    float4 b0 = *reinterpret_cast<const float4*>(W1 + (size_t)(k + 0) * 64 + ty * 4);
    float4 b1v = *reinterpret_cast<const float4*>(W1 + (size_t)(k + 1) * 64 + ty * 4);
    float4 b2v = *reinterpret_cast<const float4*>(W1 + (size_t)(k + 2) * 64 + ty * 4);
    float4 b3v = *reinterpret_cast<const float4*>(W1 + (size_t)(k + 3) * 64 + ty * 4);
    const float ar[4][4] = {{a0.x, a0.y, a0.z, a0.w}, {a1.x, a1.y, a1.z, a1.w},
                            {a2.x, a2.y, a2.z, a2.w}, {a3.x, a3.y, a3.z, a3.w}};
    const float br[4][4] = {{b0.x, b0.y, b0.z, b0.w}, {b1v.x, b1v.y, b1v.z, b1v.w},
                            {b2v.x, b2v.y, b2v.z, b2v.w}, {b3v.x, b3v.y, b3v.z, b3v.w}};
    #pragma unroll
    for (int i = 0; i < 4; ++i)
      #pragma unroll
      for (int r = 0; r < 4; ++r)
        #pragma unroll
        for (int c = 0; c < 4; ++c)
          acc[r][c] += ar[i][r] * br[i][c];
  }
  float4 bb = *reinterpret_cast<const float4*>(b1 + ty * 4);
  float4 ww = *reinterpret_cast<const float4*>(W2 + ty * 4);
  #pragma unroll
  for (int r = 0; r < 4; ++r) {
    float p = fmaxf(acc[r][0] + bb.x, 0.f) * ww.x
            + fmaxf(acc[r][1] + bb.y, 0.f) * ww.y
            + fmaxf(acc[r][2] + bb.z, 0.f) * ww.z
            + fmaxf(acc[r][3] + bb.w, 0.f) * ww.w;
    red[ty][tx * 4 + r] = p;
  }
  __syncthreads();
  if (t < 64) {
    float ssum = b2[0];
    #pragma unroll
    for (int g = 0; g < 16; ++g) ssum += red[g][t];
    int n = row0 + t;
    if (n < N_NODES) gate[n] = ssum;
  }
}

// ---------------------------------------------------------------------------
// K13: per-graph node ranges via binary search on sorted batch
// ---------------------------------------------------------------------------
__global__ void k_gptr(const int* __restrict__ batch, int* __restrict__ gptr) {
  int g = blockIdx.x * 256 + threadIdx.x;
  if (g > N_GRAPH) return;
  if (g == N_GRAPH) { gptr[g] = N_NODES; return; }
  int lo = 0, hi = N_NODES;
  while (lo < hi) {
    int mid = (lo + hi) >> 1;
    if (batch[mid] < g) lo = mid + 1; else hi = mid;
  }
  gptr[g] = lo;
}

// ---------------------------------------------------------------------------
// K14: pooling with layer-3 BN+ReLU applied on the fly (channel = thread)
// ---------------------------------------------------------------------------
__launch_bounds__(128)
__global__ void k_pool(const float* __restrict__ hAgg, const float* __restrict__ ss,
                       const float* __restrict__ gate, const int* __restrict__ gptr,
                       float* __restrict__ gr) {
  int g = blockIdx.x;
  int t = threadIdx.x;
  int p0 = gptr[g], p1 = gptr[g + 1], cnt = p1 - p0;
  float* out = gr + (size_t)g * 384;
  if (cnt == 0) { out[t] = 0.f; out[128 + t] = 0.f; out[256 + t] = 0.f; return; }
  float bg = ss[t], bb = ss[DIM + t];
  __shared__ float red[2];
  __shared__ float wbuf[128];
  __shared__ float sgm, sinv;
  float lm = -1e30f;
  for (int n = p0 + t; n < p1; n += 128) lm = fmaxf(lm, gate[n]);
  for (int off = 1; off < 64; off <<= 1) lm = fmaxf(lm, __shfl_xor(lm, off));
  if ((t & 63) == 0) red[t >> 6] = lm;
  __syncthreads();
  if (t == 0) sgm = fmaxf(red[0], red[1]);
  __syncthreads();
  float gm = sgm;
  float ls = 0.f;
  for (int n = p0 + t; n < p1; n += 128) ls += expf(gate[n] - gm);
  for (int off = 1; off < 64; off <<= 1) ls += __shfl_xor(ls, off);
  if ((t & 63) == 0) red[t >> 6] = ls;
  __syncthreads();
  if (t == 0) sinv = 1.f / ((red[0] + red[1]) + 1e-16f);
  __syncthreads();
  float inv = sinv;
  float sm = 0.f, mx = -1e30f, wa = 0.f;
  for (int c0 = p0; c0 < p1; c0 += 128) {
    int lim = min(128, p1 - c0);
    if (t < lim) wbuf[t] = expf(gate[c0 + t] - gm) * inv;
    __syncthreads();
    for (int j = 0; j < lim; ++j) {
      float v = fmaxf(hAgg[(size_t)(c0 + j) * DIM + t] * bg + bb, 0.f);
      sm += v;
      mx = fmaxf(mx, v);
      wa += v * wbuf[j];
    }
    __syncthreads();
  }
  out[t] = sm / (float)cnt;
  out[128 + t] = mx;
  out[256 + t] = wa;
}

// ---------------------------------------------------------------------------
// K15/K16: final graph MLP — 8 graphs per block, W column reused in register
// ---------------------------------------------------------------------------
__launch_bounds__(256)
__global__ void k_mlp1(const float* __restrict__ gr, const float* __restrict__ W1,
                       const float* __restrict__ b1, float* __restrict__ hid) {
  int j = threadIdx.x;            // 256 hidden
  int g0 = blockIdx.x * 8;        // 512 blocks
  float acc[8];
  float bj = b1[j];
  #pragma unroll
  for (int g = 0; g < 8; ++g) acc[g] = bj;
  for (int k = 0; k < 384; ++k) {
    float w = W1[(size_t)k * 256 + j];
    #pragma unroll
    for (int g = 0; g < 8; ++g) acc[g] += gr[(size_t)(g0 + g) * 384 + k] * w;
  }
  #pragma unroll
  for (int g = 0; g < 8; ++g) hid[(size_t)(g0 + g) * 256 + j] = fmaxf(acc[g], 0.f);
}

__launch_bounds__(128)
__global__ void k_mlp2(const float* __restrict__ hid, const float* __restrict__ W2,
                       const float* __restrict__ b2, float* __restrict__ out) {
  int j = threadIdx.x;            // 128 out
  int g0 = blockIdx.x * 8;        // 512 blocks
  float acc[8];
  float bj = b2[j];
  #pragma unroll
  for (int g = 0; g < 8; ++g) acc[g] = bj;
  for (int k = 0; k < 256; ++k) {
    float w = W2[(size_t)k * DIM + j];
    #pragma unroll
    for (int g = 0; g < 8; ++g) acc[g] += hid[(size_t)(g0 + g) * 256 + k] * w;
  }
  #pragma unroll
  for (int g = 0; g < 8; ++g) out[(size_t)(g0 + g) * DIM + j] = fmaxf(acc[g], 0.f);
}

// ---------------------------------------------------------------------------
extern "C" void kernel_launch(void* const* d_in, const int* in_sizes, int n_in,
                              void* d_out, int out_size, void* d_ws, size_t ws_size,
                              hipStream_t stream) {
  const float* x         = (const float*)d_in[0];
  const float* edge_attr = (const float*)d_in[1];
  const int*   eidx      = (const int*)d_in[2];
  const int*   batch     = (const int*)d_in[3];
  const float* W_node    = (const float*)d_in[4];
  const float* b_node    = (const float*)d_in[5];
  const float* W_edge    = (const float*)d_in[6];
  const float* b_edge    = (const float*)d_in[7];
  const float* W_lin     = (const float*)d_in[8];
  const float* att_src   = (const float*)d_in[9];
  const float* att_dst   = (const float*)d_in[10];
  const float* W_eproj   = (const float*)d_in[11];
  const float* att_edge  = (const float*)d_in[12];
  const float* gat_bias  = (const float*)d_in[13];
  const float* bn_gamma  = (const float*)d_in[14];
  const float* bn_beta   = (const float*)d_in[15];
  const float* gate_W1   = (const float*)d_in[16];
  const float* gate_b1   = (const float*)d_in[17];
  const float* gate_W2   = (const float*)d_in[18];
  const float* gate_b2   = (const float*)d_in[19];
  const float* mlp_W1    = (const float*)d_in[20];
  const float* mlp_b1    = (const float*)d_in[21];
  const float* mlp_W2    = (const float*)d_in[22];
  const float* mlp_b2    = (const float*)d_in[23];
  const int* src = eidx;
  const int* dst = eidx + N_EDGES;

  char* p = (char*)d_ws;
  auto take = [&](size_t bytes) -> char* {
    char* r = p;
    p += (bytes + 255) & ~(size_t)255;
    return r;
  };
  float* hEnc   = (float*)take((size_t)N_NODES * DIM * 4);   // encoder out == residual
  float* hAgg   = (float*)take((size_t)N_NODES * DIM * 4);   // raw aggregate out
  unsigned short* hp = (unsigned short*)take((size_t)N_NODES * DIM * 2);  // bf16 messages
  float* a_s    = (float*)take((size_t)N_NODES * 8 * 4);
  float* a_d    = (float*)take((size_t)N_NODES * 8 * 4);
  int2*  cpair  = (int2*)take((size_t)N_EDGES * 8);
  float* cea    = (float*)take((size_t)N_EDGES * 3 * 4);
  float* easum  = (float*)take((size_t)N_NODES * 3 * 4);
  char* zbase = p;                               // ---- zeroed region ----
  int*   deg    = (int*)take((size_t)N_NODES * 4);
  int*   fill   = (int*)take((size_t)N_NODES * 4);
  size_t zbytes = (size_t)(p - zbase);           // -----------------------
  int*   rp     = (int*)take((size_t)(N_NODES + 1) * 4);
  int*   bsum   = (int*)take(1024 * 4);
  float* small3 = (float*)take(96 * 4);
  float* biasE  = (float*)take(32 * 4);
  double* partial = (double*)take((size_t)BN_BLK * 256 * 8);
  float* ssAll  = (float*)take(4 * 256 * 4);
  float* gate   = (float*)take((size_t)N_NODES * 4);
  int*   gptr   = (int*)take((size_t)(N_GRAPH + 1) * 4);
  float* gr     = (float*)take((size_t)N_GRAPH * 384 * 4);
  float* hid    = (float*)take((size_t)N_GRAPH * 256 * 4);

  hipMemsetAsync(zbase, 0, zbytes, stream);
  k_prep<<<1, 256, 0, stream>>>(W_eproj, att_edge, W_edge, b_edge, small3, biasE);
  k_encode<<<(N_NODES * DIM) / 256, 256, 0, stream>>>(x, W_node, b_node, hEnc);
  k_deg<<<(N_EDGES + 255) / 256, 256, 0, stream>>>(dst, deg);
  int nb = (N_NODES + 255) / 256;
  k_scan1<<<nb, 256, 0, stream>>>(deg, rp, bsum);
  k_scan2<<<1, 512, 0, stream>>>(bsum, nb);
  k_scan3<<<nb, 256, 0, stream>>>(rp, bsum);
  k_scatter<<<(N_EDGES + 255) / 256, 256, 0, stream>>>(src, dst, edge_attr, rp, fill, cpair, cea);
  k_easum<<<nb, 256, 0, stream>>>(rp, cea, easum);

  for (int l = 0; l < LAYERS; ++l) {
    const float* hsrc = (l == 0) ? hEnc : hAgg;
    int mode = (l == 0) ? 0 : ((l == 3) ? 2 : 1);
    k_gemm_hp<<<(N_NODES + 127) / 128, 256, 0, stream>>>(
        hsrc, hEnc, ssAll + (l > 0 ? (l - 1) * 256 : 0), mode,
        W_lin + (size_t)l * DIM * DIM,
        att_src + l * HEADS * CHD, att_dst + l * HEADS * CHD, hp, a_s, a_d);
    k_attagg<<<(N_NODES + 3) / 4, 256, 0, stream>>>(
        hp, rp, cpair, cea, a_s, a_d, easum, small3, biasE,
        gat_bias + l * DIM, hAgg, l);
    k_bnstat<<<BN_BLK, 256, 0, stream>>>(hAgg, partial);
    k_bnfin<<<1, 128, 0, stream>>>(partial, bn_gamma + l * DIM, bn_beta + l * DIM,
                                   ssAll + l * 256);
  }

  const float* ss3 = ssAll + 3 * 256;
  k_gate<<<(N_NODES + 63) / 64, 256, 0, stream>>>(hAgg, ss3, gate_W1, gate_b1, gate_W2, gate_b2, gate);
  k_gptr<<<(N_GRAPH + 1 + 255) / 256, 256, 0, stream>>>(batch, gptr);
  k_pool<<<N_GRAPH, 128, 0, stream>>>(hAgg, ss3, gate, gptr, gr);
  k_mlp1<<<N_GRAPH / 8, 256, 0, stream>>>(gr, mlp_W1, mlp_b1, hid);
  k_mlp2<<<N_GRAPH / 8, 128, 0, stream>>>(hid, mlp_W2, mlp_b2, (float*)d_out);
}

// Round 11
// 1069.888 us; speedup vs baseline: 1.0522x; 1.0522x over previous
//
#include <hip/hip_runtime.h>
#include <math.h>

#define N_NODES 100000
#define N_EDGES 400000
#define N_GRAPH 4096
#define DIM 128
#define HEADS 8
#define CHD 16
#define LAYERS 4
#define EPS_BN 1e-5f
#define BN_BLK 256

// bf16 helpers (RN-even pack, cheap unpack)
static __device__ __forceinline__ unsigned short f2bf(float f) {
  unsigned int u = __float_as_uint(f);
  u += 0x7FFFu + ((u >> 16) & 1u);
  return (unsigned short)(u >> 16);
}

// ---------------------------------------------------------------------------
// K1: fold W_eproj/att_edge/W_edge/b_edge into small3[L][3][8] + biasE[L][8]
// ---------------------------------------------------------------------------
__global__ void k_prep(const float* __restrict__ W_eproj, const float* __restrict__ att_edge,
                       const float* __restrict__ W_edge, const float* __restrict__ b_edge,
                       float* __restrict__ small3, float* __restrict__ biasE) {
  __shared__ float sw[DIM * 32];   // w_e_att[d][l*8+h]
  int t = threadIdx.x;
  for (int e = t; e < DIM * 32; e += 256) {
    int d = e >> 5, lh = e & 31, l = lh >> 3, hh = lh & 7;
    float s = 0.f;
    const float* wp = W_eproj + ((size_t)l * DIM + d) * DIM + hh * CHD;
    const float* ap = att_edge + (l * HEADS + hh) * CHD;
    #pragma unroll
    for (int c = 0; c < CHD; ++c) s += wp[c] * ap[c];
    sw[e] = s;
  }
  __syncthreads();
  if (t < 96) {                       // small3[l][k][h]
    int l = t / 24, r = t % 24, k = r / 8, hh = r % 8;
    float s = 0.f;
    for (int d = 0; d < DIM; ++d) s += W_edge[k * DIM + d] * sw[d * 32 + l * 8 + hh];
    small3[t] = s;
  } else if (t < 128) {               // biasE[l][h]
    int t2 = t - 96, l = t2 / 8, hh = t2 % 8;
    float s = 0.f;
    for (int d = 0; d < DIM; ++d) s += b_edge[d] * sw[d * 32 + l * 8 + hh];
    biasE[t2] = s;
  }
}

// ---------------------------------------------------------------------------
// K2: node encoder hEnc = x @ W_node + b_node (hEnc doubles as residual)
// ---------------------------------------------------------------------------
__global__ void k_encode(const float* __restrict__ x, const float* __restrict__ Wn,
                         const float* __restrict__ bn, float* __restrict__ hEnc) {
  __shared__ float sw[9 * DIM];
  __shared__ float sb[DIM];
  int t = threadIdx.x;
  for (int i = t; i < 9 * DIM; i += 256) sw[i] = Wn[i];
  if (t < DIM) sb[t] = bn[t];
  __syncthreads();
  size_t id = (size_t)blockIdx.x * 256 + t;
  if (id >= (size_t)N_NODES * DIM) return;
  int n = (int)(id >> 7), d = (int)(id & 127);
  float s = sb[d];
  const float* xr = x + (size_t)n * 9;
  #pragma unroll
  for (int k = 0; k < 9; ++k) s += xr[k] * sw[k * DIM + d];
  hEnc[id] = s;
}

// ---------------------------------------------------------------------------
// K3: in-degree histogram (int atomics only)
// ---------------------------------------------------------------------------
__global__ void k_deg(const int* __restrict__ dst, int* __restrict__ deg) {
  int i = blockIdx.x * 256 + threadIdx.x;
  if (i >= N_EDGES) return;
  atomicAdd(&deg[dst[i]], 1);
}

// ---------------------------------------------------------------------------
// K4: 3-kernel exclusive scan of deg -> row_ptr
// ---------------------------------------------------------------------------
__global__ void k_scan1(const int* __restrict__ deg, int* __restrict__ rp, int* __restrict__ bsum) {
  __shared__ int s[256];
  int t = threadIdx.x, i = blockIdx.x * 256 + t;
  int v = (i < N_NODES) ? deg[i] : 0;
  s[t] = v;
  __syncthreads();
  for (int off = 1; off < 256; off <<= 1) {
    int u = (t >= off) ? s[t - off] : 0;
    __syncthreads();
    s[t] += u;
    __syncthreads();
  }
  if (i < N_NODES) rp[i] = s[t] - v;
  if (t == 255) bsum[blockIdx.x] = s[255];
}

__global__ void k_scan2(int* __restrict__ bsum, int nb) {
  __shared__ int s[512];
  int t = threadIdx.x;
  int v = (t < nb) ? bsum[t] : 0;
  s[t] = v;
  __syncthreads();
  for (int off = 1; off < 512; off <<= 1) {
    int u = (t >= off) ? s[t - off] : 0;
    __syncthreads();
    s[t] += u;
    __syncthreads();
  }
  if (t < nb) bsum[t] = s[t] - v;
}

__global__ void k_scan3(int* __restrict__ rp, const int* __restrict__ bsum) {
  int i = blockIdx.x * 256 + threadIdx.x;
  if (i < N_NODES) rp[i] += bsum[blockIdx.x];
  if (blockIdx.x == 0 && threadIdx.x == 0) rp[N_NODES] = N_EDGES;
}

// ---------------------------------------------------------------------------
// K5: CSR scatter — stores (src,dst) pair and the edge_attr row at the slot
// ---------------------------------------------------------------------------
__global__ void k_scatter(const int* __restrict__ src, const int* __restrict__ dst,
                          const float* __restrict__ ea, const int* __restrict__ rp,
                          int* __restrict__ fill, int2* __restrict__ cpair,
                          float* __restrict__ cea) {
  int i = blockIdx.x * 256 + threadIdx.x;
  if (i >= N_EDGES) return;
  int d = dst[i];
  int p = rp[d] + atomicAdd(&fill[d], 1);
  cpair[p] = make_int2(src[i], d);
  cea[(size_t)p * 3 + 0] = ea[(size_t)i * 3 + 0];
  cea[(size_t)p * 3 + 1] = ea[(size_t)i * 3 + 1];
  cea[(size_t)p * 3 + 2] = ea[(size_t)i * 3 + 2];
}

// ---------------------------------------------------------------------------
// K5b: easum[n] = contiguous sum of cea over the node's CSR range
// ---------------------------------------------------------------------------
__global__ void k_easum(const int* __restrict__ rp, const float* __restrict__ cea,
                        float* __restrict__ easum) {
  int n = blockIdx.x * 256 + threadIdx.x;
  if (n >= N_NODES) return;
  int p0 = rp[n], p1 = rp[n + 1];
  float s0 = 0.f, s1 = 0.f, s2 = 0.f;
  for (int p = p0; p < p1; ++p) {
    s0 += cea[(size_t)p * 3 + 0];
    s1 += cea[(size_t)p * 3 + 1];
    s2 += cea[(size_t)p * 3 + 2];
  }
  easum[n * 3 + 0] = s0;
  easum[n * 3 + 1] = s1;
  easum[n * 3 + 2] = s2;
}

// ---------------------------------------------------------------------------
// K6: hp = f(h) @ W_lin[l], 128x128 tile, acc[8][8]/thread, conflict-free LDS.
// hp is stored BF16 (messages only; a_s/a_d stay fp32 from fp32 accumulators).
// mode 0: raw rows; 1: relu(v*g+b); 2: relu(v*g+b)+hEnc (residual).
// ---------------------------------------------------------------------------
__launch_bounds__(256)
__global__ void k_gemm_hp(const float* __restrict__ hsrc, const float* __restrict__ hEnc,
                          const float* __restrict__ ssv, int mode,
                          const float* __restrict__ W,
                          const float* __restrict__ attS, const float* __restrict__ attD,
                          unsigned short* __restrict__ hp, float* __restrict__ a_s,
                          float* __restrict__ a_d) {
  __shared__ float sW[32 * DIM];    // 16 KB: W chunk, 32 k-rows x 128 cols
  __shared__ float sH[128 * 32];    // 16 KB: H chunk, swizzled float4 slots
  int t = threadIdx.x;
  int row0 = blockIdx.x * 128;
  int tx = t & 15, ty = t >> 4;
  int r0 = ty * 8;                  // 8 output rows per thread
  int cA = tx * 4;                  // first output col quad
  int cB = 64 + tx * 4;             // second output col quad
  int swz = ty & 7;
  float acc[8][8] = {};
  for (int kk = 0; kk < DIM; kk += 32) {
    #pragma unroll
    for (int i = 0; i < 4; ++i) {   // W chunk: contiguous per row
      int e = t + i * 256;
      int row = e >> 5, col4 = (e & 31) << 2;
      *reinterpret_cast<float4*>(&sW[row * DIM + col4]) =
          *reinterpret_cast<const float4*>(W + (size_t)(kk + row) * DIM + col4);
    }
    #pragma unroll
    for (int i = 0; i < 4; ++i) {   // H chunk (+BN), swizzled placement
      int e = t + i * 256;
      int rr = e >> 3, c4 = e & 7;
      int grr = row0 + rr;
      int col = kk + c4 * 4;
      float4 v = make_float4(0.f, 0.f, 0.f, 0.f);
      if (grr < N_NODES) {
        v = *reinterpret_cast<const float4*>(hsrc + (size_t)grr * DIM + col);
        if (mode >= 1) {
          float4 g = *reinterpret_cast<const float4*>(ssv + col);
          float4 b = *reinterpret_cast<const float4*>(ssv + DIM + col);
          v.x = fmaxf(v.x * g.x + b.x, 0.f);
          v.y = fmaxf(v.y * g.y + b.y, 0.f);
          v.z = fmaxf(v.z * g.z + b.z, 0.f);
          v.w = fmaxf(v.w * g.w + b.w, 0.f);
          if (mode == 2) {
            float4 r4 = *reinterpret_cast<const float4*>(hEnc + (size_t)grr * DIM + col);
            v.x += r4.x; v.y += r4.y; v.z += r4.z; v.w += r4.w;
          }
        }
      }
      int slot = c4 ^ ((rr >> 3) & 7);
      *reinterpret_cast<float4*>(&sH[rr * 32 + slot * 4]) = v;
    }
    __syncthreads();
    for (int k = 0; k < 32; k += 4) {
      int c4s = (k >> 2) ^ swz;
      float4 a[8];
      #pragma unroll
      for (int r = 0; r < 8; ++r)
        a[r] = *reinterpret_cast<const float4*>(&sH[(r0 + r) * 32 + c4s * 4]);
      #pragma unroll
      for (int k2 = 0; k2 < 4; ++k2) {
        float4 wA = *reinterpret_cast<const float4*>(&sW[(k + k2) * DIM + cA]);
        float4 wB = *reinterpret_cast<const float4*>(&sW[(k + k2) * DIM + cB]);
        #pragma unroll
        for (int r = 0; r < 8; ++r) {
          float av = (k2 == 0) ? a[r].x : (k2 == 1) ? a[r].y : (k2 == 2) ? a[r].z : a[r].w;
          acc[r][0] += av * wA.x; acc[r][1] += av * wA.y;
          acc[r][2] += av * wA.z; acc[r][3] += av * wA.w;
          acc[r][4] += av * wB.x; acc[r][5] += av * wB.y;
          acc[r][6] += av * wB.z; acc[r][7] += av * wB.w;
        }
      }
    }
    __syncthreads();
  }
  // epilogue: cols cA..cA+3 = head hA; cB quad = head hA+4; reduce over tx&3
  int hA = tx >> 2;
  int cin0 = (tx & 3) * 4;
  float wsA[4], wdA[4], wsB[4], wdB[4];
  #pragma unroll
  for (int j = 0; j < 4; ++j) {
    wsA[j] = attS[hA * CHD + cin0 + j];
    wdA[j] = attD[hA * CHD + cin0 + j];
    wsB[j] = attS[(hA + 4) * CHD + cin0 + j];
    wdB[j] = attD[(hA + 4) * CHD + cin0 + j];
  }
  #pragma unroll
  for (int r = 0; r < 8; ++r) {
    int n = row0 + r0 + r;
    float psA = 0.f, pdA = 0.f, psB = 0.f, pdB = 0.f;
    #pragma unroll
    for (int j = 0; j < 4; ++j) {
      psA += acc[r][j] * wsA[j];
      pdA += acc[r][j] * wdA[j];
      psB += acc[r][4 + j] * wsB[j];
      pdB += acc[r][4 + j] * wdB[j];
    }
    psA += __shfl_xor(psA, 1); psA += __shfl_xor(psA, 2);
    pdA += __shfl_xor(pdA, 1); pdA += __shfl_xor(pdA, 2);
    psB += __shfl_xor(psB, 1); psB += __shfl_xor(psB, 2);
    pdB += __shfl_xor(pdB, 1); pdB += __shfl_xor(pdB, 2);
    if (n < N_NODES) {
      ushort4 pa = make_ushort4(f2bf(acc[r][0]), f2bf(acc[r][1]),
                                f2bf(acc[r][2]), f2bf(acc[r][3]));
      ushort4 pb = make_ushort4(f2bf(acc[r][4]), f2bf(acc[r][5]),
                                f2bf(acc[r][6]), f2bf(acc[r][7]));
      *reinterpret_cast<ushort4*>(hp + (size_t)n * DIM + cA) = pa;
      *reinterpret_cast<ushort4*>(hp + (size_t)n * DIM + cB) = pb;
      if ((tx & 3) == 0) {
        a_s[(size_t)n * HEADS + hA] = psA;
        a_s[(size_t)n * HEADS + hA + 4] = psB;
        a_d[(size_t)n * HEADS + hA] = pdA;
        a_d[(size_t)n * HEADS + hA + 4] = pdB;
      }
    }
  }
}

// ---------------------------------------------------------------------------
// K7: FUSED alpha + segment-softmax + aggregation. One wave per node.
// Gather-ILP version: lane owns channels {2*lane, 2*lane+1} (head lane>>3),
// so each entry is ONE 4B uint load per lane (full 256B row coalesced).
// Per 8-entry group: batch all shfl(src), then issue all <=8 row loads
// back-to-back into register arrays (unrolled, compile-time indices),
// then consume. Raises gather MLP from ~2 to ~8 outstanding.
// ---------------------------------------------------------------------------
__launch_bounds__(256)
__global__ void k_attagg(const unsigned short* __restrict__ hp, const int* __restrict__ rp,
                         const int2* __restrict__ cpair, const float* __restrict__ cea,
                         const float* __restrict__ a_s, const float* __restrict__ a_d,
                         const float* __restrict__ easum, const float* __restrict__ small3,
                         const float* __restrict__ biasE, const float* __restrict__ gbias,
                         float* __restrict__ out, int l) {
  __shared__ float sc[32];   // small3[l] (24) + biasE[l] (8)
  int t = threadIdx.x;
  if (t < 24) sc[t] = small3[l * 24 + t];
  else if (t < 32) sc[t] = biasE[l * 8 + (t - 24)];
  __syncthreads();
  int wv = t >> 6, lane = t & 63;
  int n = blockIdx.x * 4 + wv;
  if (n >= N_NODES) return;
  int p0 = rp[n], p1 = rp[n + 1];
  int deg = p1 - p0;
  int hh = lane & 7, sub = lane >> 3;
  int hc = lane >> 3;                 // head owning channels 2*lane, 2*lane+1
  float adh = a_d[(size_t)n * 8 + hh];
  float dg = (float)deg, invd = 1.f / fmaxf(dg, 1.f);
  float se0 = easum[n * 3 + 0], se1 = easum[n * 3 + 1], se2 = easum[n * 3 + 2];
  float aeS = (se0 * sc[hh] + se1 * sc[8 + hh] + se2 * sc[16 + hh] + dg * sc[24 + hh]) * invd;
  float lgS = a_s[(size_t)n * 8 + hh] + adh + aeS;
  lgS = (lgS > 0.f) ? lgS : 0.2f * lgS;
  float eS = expf(lgS);
  float s = (sub == 0) ? eS : 0.f;
  float acc0 = 0.f, acc1 = 0.f;
  for (int j0 = 0; j0 < deg; j0 += 8) {
    int idx = j0 + sub;
    float e = 0.f;
    int myc = 0;
    if (idx < deg) {
      int p = p0 + idx;
      myc = cpair[p].x;
      float c0v = cea[(size_t)p * 3 + 0], c1v = cea[(size_t)p * 3 + 1], c2v = cea[(size_t)p * 3 + 2];
      float ae = c0v * sc[hh] + c1v * sc[8 + hh] + c2v * sc[16 + hh] + sc[24 + hh];
      float lg = a_s[(size_t)myc * 8 + hh] + adh + ae;
      lg = (lg > 0.f) ? lg : 0.2f * lg;
      e = expf(lg);
    }
    s += e;
    int kmax = min(8, deg - j0);
    int sas[8];
    unsigned int u[8];
    #pragma unroll
    for (int k = 0; k < 8; ++k)
      if (k < kmax) sas[k] = __shfl(myc, k * 8);       // lane (sub=k,hh=0)
    #pragma unroll
    for (int k = 0; k < 8; ++k)
      if (k < kmax)
        u[k] = *reinterpret_cast<const unsigned int*>(hp + (size_t)sas[k] * DIM + 2 * lane);
    #pragma unroll
    for (int k = 0; k < 8; ++k)
      if (k < kmax) {
        float w = __shfl(e, k * 8 + hc);
        acc0 += w * __uint_as_float(u[k] << 16);
        acc1 += w * __uint_as_float(u[k] & 0xFFFF0000u);
      }
  }
  s += __shfl_xor(s, 8); s += __shfl_xor(s, 16); s += __shfl_xor(s, 32);
  float inv = 1.f / (s + 1e-16f);
  float iH = __shfl(inv, hc);
  float wS = __shfl(eS, hc);
  unsigned int us = *reinterpret_cast<const unsigned int*>(hp + (size_t)n * DIM + 2 * lane);
  acc0 += wS * __uint_as_float(us << 16);
  acc1 += wS * __uint_as_float(us & 0xFFFF0000u);
  float2 gb = *reinterpret_cast<const float2*>(gbias + 2 * lane);
  float2 o = make_float2(acc0 * iH + gb.x, acc1 * iH + gb.y);
  *reinterpret_cast<float2*>(out + (size_t)n * DIM + 2 * lane) = o;
}

// ---------------------------------------------------------------------------
// K9: BN stats -> per-block partials (no atomics). K10: reduce + scale/shift.
// ---------------------------------------------------------------------------
__launch_bounds__(256)
__global__ void k_bnstat(const float* __restrict__ h, double* __restrict__ partial) {
  int t = threadIdx.x;
  int c = t & 127, half = t >> 7;
  double s = 0.0, q = 0.0;
  for (int n = blockIdx.x * 2 + half; n < N_NODES; n += BN_BLK * 2) {
    float v = h[(size_t)n * DIM + c];
    s += (double)v;
    q += (double)v * (double)v;
  }
  __shared__ double sd[512];
  sd[t] = s; sd[256 + t] = q;
  __syncthreads();
  if (t < 128) {
    s = sd[t] + sd[t + 128];
    q = sd[256 + t] + sd[256 + t + 128];
    partial[(size_t)blockIdx.x * 256 + t] = s;
    partial[(size_t)blockIdx.x * 256 + 128 + t] = q;
  }
}

__global__ void k_bnfin(const double* __restrict__ partial, const float* __restrict__ gamma,
                        const float* __restrict__ beta, float* __restrict__ ss) {
  int c = threadIdx.x;   // 128
  double s = 0.0, q = 0.0;
  for (int b = 0; b < BN_BLK; ++b) {
    s += partial[(size_t)b * 256 + c];
    q += partial[(size_t)b * 256 + 128 + c];
  }
  double mu = s / (double)N_NODES;
  double var = q / (double)N_NODES - mu * mu;
  if (var < 0.0) var = 0.0;
  float rs = rsqrtf((float)var + EPS_BN);
  float g = gamma[c] * rs;
  ss[c] = g;
  ss[DIM + c] = beta[c] - (float)mu * g;
}

// ---------------------------------------------------------------------------
// K12: gate MLP as register-blocked tile GEMM; layer-3 BN+ReLU fused in staging
// ---------------------------------------------------------------------------
__launch_bounds__(256, 2)
__global__ void k_gate(const float* __restrict__ hAgg, const float* __restrict__ ss,
                       const float* __restrict__ W1, const float* __restrict__ b1,
                       const float* __restrict__ W2, const float* __restrict__ b2,
                       float* __restrict__ gate) {
  __shared__ float sHT[128][64];   // 32 KB: sHT[k][node]
  __shared__ float red[16][64];    // 4 KB
  int t = threadIdx.x;
  int row0 = blockIdx.x * 64;
  {
    int node = t & 63, kq = t >> 6;
    int gn = row0 + node;
    const float* hr = hAgg + (size_t)gn * DIM + kq * 32;
    #pragma unroll
    for (int c = 0; c < 8; ++c) {
      int col = kq * 32 + c * 4;
      float4 v = (gn < N_NODES) ? *reinterpret_cast<const float4*>(hr + c * 4)
                                : make_float4(0.f, 0.f, 0.f, 0.f);
      float4 g = *reinterpret_cast<const float4*>(ss + col);
      float4 b = *reinterpret_cast<const float4*>(ss + DIM + col);
      sHT[col + 0][node] = fmaxf(v.x * g.x + b.x, 0.f);
      sHT[col + 1][node] = fmaxf(v.y * g.y + b.y, 0.f);
      sHT[col + 2][node] = fmaxf(v.z * g.z + b.z, 0.f);
      sHT[col + 3][node] = fmaxf(v.w * g.w + b.w, 0.f);
    }
  }
  __syncthreads();
  int tx = t & 15, ty = t >> 4;
  float acc[4][4] = {};
  for (int k = 0; k < 128; k += 4) {
    float4 a0 = *reinterpret_cast<const float4*>(&sHT[k + 0][tx * 4]);
    float4 a1 = *reinterpret_cast<const float4*>(&sHT[k + 1][tx * 4]);
    float4 a2 = *reinterpret_cast<const float4*>(&sHT[k + 2][tx * 4]);
    float4 a3 = *reinterpret_cast<const float4*>(&sHT[k + 3][tx * 4]);
    float4 b0 = *reinterpret_cast<const float4*>(W1 + (size_t)(k + 0) * 64 + ty * 4);
    float4 b1v = *reinterpret_cast<const float4*>(W1 + (size_t)(k + 1) * 64 + ty * 4);
    float4 b2v = *reinterpret_cast<const float4*>(W1 + (size_t)(k + 2) * 64 + ty * 4);
    float4 b3v = *reinterpret_cast<const float4*>(W1 + (size_t)(k + 3) * 64 + ty * 4);
    const float ar[4][4] = {{a0.x, a0.y, a0.z, a0.w}, {a1.x, a1.y, a1.z, a1.w},
                            {a2.x, a2.y, a2.z, a2.w}, {a3.x, a3.y, a3.z, a3.w}};
    const float br[4][4] = {{b0.x, b0.y, b0.z, b0.w}, {b1v.x, b1v.y, b1v.z, b1v.w},
                            {b2v.x, b2v.y, b2v.z, b2v.w}, {b3v.x, b3v.y, b3v.z, b3v.w}};
    #pragma unroll
    for (int i = 0; i < 4; ++i)
      #pragma unroll
      for (int r = 0; r < 4; ++r)
        #pragma unroll
        for (int c = 0; c < 4; ++c)
          acc[r][c] += ar[i][r] * br[i][c];
  }
  float4 bb = *reinterpret_cast<const float4*>(b1 + ty * 4);
  float4 ww = *reinterpret_cast<const float4*>(W2 + ty * 4);
  #pragma unroll
  for (int r = 0; r < 4; ++r) {
    float p = fmaxf(acc[r][0] + bb.x, 0.f) * ww.x
            + fmaxf(acc[r][1] + bb.y, 0.f) * ww.y
            + fmaxf(acc[r][2] + bb.z, 0.f) * ww.z
            + fmaxf(acc[r][3] + bb.w, 0.f) * ww.w;
    red[ty][tx * 4 + r] = p;
  }
  __syncthreads();
  if (t < 64) {
    float ssum = b2[0];
    #pragma unroll
    for (int g = 0; g < 16; ++g) ssum += red[g][t];
    int n = row0 + t;
    if (n < N_NODES) gate[n] = ssum;
  }
}

// ---------------------------------------------------------------------------
// K13: per-graph node ranges via binary search on sorted batch
// ---------------------------------------------------------------------------
__global__ void k_gptr(const int* __restrict__ batch, int* __restrict__ gptr) {
  int g = blockIdx.x * 256 + threadIdx.x;
  if (g > N_GRAPH) return;
  if (g == N_GRAPH) { gptr[g] = N_NODES; return; }
  int lo = 0, hi = N_NODES;
  while (lo < hi) {
    int mid = (lo + hi) >> 1;
    if (batch[mid] < g) lo = mid + 1; else hi = mid;
  }
  gptr[g] = lo;
}

// ---------------------------------------------------------------------------
// K14: pooling with layer-3 BN+ReLU applied on the fly (channel = thread)
// ---------------------------------------------------------------------------
__launch_bounds__(128)
__global__ void k_pool(const float* __restrict__ hAgg, const float* __restrict__ ss,
                       const float* __restrict__ gate, const int* __restrict__ gptr,
                       float* __restrict__ gr) {
  int g = blockIdx.x;
  int t = threadIdx.x;
  int p0 = gptr[g], p1 = gptr[g + 1], cnt = p1 - p0;
  float* out = gr + (size_t)g * 384;
  if (cnt == 0) { out[t] = 0.f; out[128 + t] = 0.f; out[256 + t] = 0.f; return; }
  float bg = ss[t], bb = ss[DIM + t];
  __shared__ float red[2];
  __shared__ float wbuf[128];
  __shared__ float sgm, sinv;
  float lm = -1e30f;
  for (int n = p0 + t; n < p1; n += 128) lm = fmaxf(lm, gate[n]);
  for (int off = 1; off < 64; off <<= 1) lm = fmaxf(lm, __shfl_xor(lm, off));
  if ((t & 63) == 0) red[t >> 6] = lm;
  __syncthreads();
  if (t == 0) sgm = fmaxf(red[0], red[1]);
  __syncthreads();
  float gm = sgm;
  float ls = 0.f;
  for (int n = p0 + t; n < p1; n += 128) ls += expf(gate[n] - gm);
  for (int off = 1; off < 64; off <<= 1) ls += __shfl_xor(ls, off);
  if ((t & 63) == 0) red[t >> 6] = ls;
  __syncthreads();
  if (t == 0) sinv = 1.f / ((red[0] + red[1]) + 1e-16f);
  __syncthreads();
  float inv = sinv;
  float sm = 0.f, mx = -1e30f, wa = 0.f;
  for (int c0 = p0; c0 < p1; c0 += 128) {
    int lim = min(128, p1 - c0);
    if (t < lim) wbuf[t] = expf(gate[c0 + t] - gm) * inv;
    __syncthreads();
    for (int j = 0; j < lim; ++j) {
      float v = fmaxf(hAgg[(size_t)(c0 + j) * DIM + t] * bg + bb, 0.f);
      sm += v;
      mx = fmaxf(mx, v);
      wa += v * wbuf[j];
    }
    __syncthreads();
  }
  out[t] = sm / (float)cnt;
  out[128 + t] = mx;
  out[256 + t] = wa;
}

// ---------------------------------------------------------------------------
// K15/K16: final graph MLP — 8 graphs per block, W column reused in register
// ---------------------------------------------------------------------------
__launch_bounds__(256)
__global__ void k_mlp1(const float* __restrict__ gr, const float* __restrict__ W1,
                       const float* __restrict__ b1, float* __restrict__ hid) {
  int j = threadIdx.x;            // 256 hidden
  int g0 = blockIdx.x * 8;        // 512 blocks
  float acc[8];
  float bj = b1[j];
  #pragma unroll
  for (int g = 0; g < 8; ++g) acc[g] = bj;
  for (int k = 0; k < 384; ++k) {
    float w = W1[(size_t)k * 256 + j];
    #pragma unroll
    for (int g = 0; g < 8; ++g) acc[g] += gr[(size_t)(g0 + g) * 384 + k] * w;
  }
  #pragma unroll
  for (int g = 0; g < 8; ++g) hid[(size_t)(g0 + g) * 256 + j] = fmaxf(acc[g], 0.f);
}

__launch_bounds__(128)
__global__ void k_mlp2(const float* __restrict__ hid, const float* __restrict__ W2,
                       const float* __restrict__ b2, float* __restrict__ out) {
  int j = threadIdx.x;            // 128 out
  int g0 = blockIdx.x * 8;        // 512 blocks
  float acc[8];
  float bj = b2[j];
  #pragma unroll
  for (int g = 0; g < 8; ++g) acc[g] = bj;
  for (int k = 0; k < 256; ++k) {
    float w = W2[(size_t)k * DIM + j];
    #pragma unroll
    for (int g = 0; g < 8; ++g) acc[g] += hid[(size_t)(g0 + g) * 256 + k] * w;
  }
  #pragma unroll
  for (int g = 0; g < 8; ++g) out[(size_t)(g0 + g) * DIM + j] = fmaxf(acc[g], 0.f);
}

// ---------------------------------------------------------------------------
extern "C" void kernel_launch(void* const* d_in, const int* in_sizes, int n_in,
                              void* d_out, int out_size, void* d_ws, size_t ws_size,
                              hipStream_t stream) {
  const float* x         = (const float*)d_in[0];
  const float* edge_attr = (const float*)d_in[1];
  const int*   eidx      = (const int*)d_in[2];
  const int*   batch     = (const int*)d_in[3];
  const float* W_node    = (const float*)d_in[4];
  const float* b_node    = (const float*)d_in[5];
  const float* W_edge    = (const float*)d_in[6];
  const float* b_edge    = (const float*)d_in[7];
  const float* W_lin     = (const float*)d_in[8];
  const float* att_src   = (const float*)d_in[9];
  const float* att_dst   = (const float*)d_in[10];
  const float* W_eproj   = (const float*)d_in[11];
  const float* att_edge  = (const float*)d_in[12];
  const float* gat_bias  = (const float*)d_in[13];
  const float* bn_gamma  = (const float*)d_in[14];
  const float* bn_beta   = (const float*)d_in[15];
  const float* gate_W1   = (const float*)d_in[16];
  const float* gate_b1   = (const float*)d_in[17];
  const float* gate_W2   = (const float*)d_in[18];
  const float* gate_b2   = (const float*)d_in[19];
  const float* mlp_W1    = (const float*)d_in[20];
  const float* mlp_b1    = (const float*)d_in[21];
  const float* mlp_W2    = (const float*)d_in[22];
  const float* mlp_b2    = (const float*)d_in[23];
  const int* src = eidx;
  const int* dst = eidx + N_EDGES;

  char* p = (char*)d_ws;
  auto take = [&](size_t bytes) -> char* {
    char* r = p;
    p += (bytes + 255) & ~(size_t)255;
    return r;
  };
  float* hEnc   = (float*)take((size_t)N_NODES * DIM * 4);   // encoder out == residual
  float* hAgg   = (float*)take((size_t)N_NODES * DIM * 4);   // raw aggregate out
  unsigned short* hp = (unsigned short*)take((size_t)N_NODES * DIM * 2);  // bf16 messages
  float* a_s    = (float*)take((size_t)N_NODES * 8 * 4);
  float* a_d    = (float*)take((size_t)N_NODES * 8 * 4);
  int2*  cpair  = (int2*)take((size_t)N_EDGES * 8);
  float* cea    = (float*)take((size_t)N_EDGES * 3 * 4);
  float* easum  = (float*)take((size_t)N_NODES * 3 * 4);
  char* zbase = p;                               // ---- zeroed region ----
  int*   deg    = (int*)take((size_t)N_NODES * 4);
  int*   fill   = (int*)take((size_t)N_NODES * 4);
  size_t zbytes = (size_t)(p - zbase);           // -----------------------
  int*   rp     = (int*)take((size_t)(N_NODES + 1) * 4);
  int*   bsum   = (int*)take(1024 * 4);
  float* small3 = (float*)take(96 * 4);
  float* biasE  = (float*)take(32 * 4);
  double* partial = (double*)take((size_t)BN_BLK * 256 * 8);
  float* ssAll  = (float*)take(4 * 256 * 4);
  float* gate   = (float*)take((size_t)N_NODES * 4);
  int*   gptr   = (int*)take((size_t)(N_GRAPH + 1) * 4);
  float* gr     = (float*)take((size_t)N_GRAPH * 384 * 4);
  float* hid    = (float*)take((size_t)N_GRAPH * 256 * 4);

  hipMemsetAsync(zbase, 0, zbytes, stream);
  k_prep<<<1, 256, 0, stream>>>(W_eproj, att_edge, W_edge, b_edge, small3, biasE);
  k_encode<<<(N_NODES * DIM) / 256, 256, 0, stream>>>(x, W_node, b_node, hEnc);
  k_deg<<<(N_EDGES + 255) / 256, 256, 0, stream>>>(dst, deg);
  int nb = (N_NODES + 255) / 256;
  k_scan1<<<nb, 256, 0, stream>>>(deg, rp, bsum);
  k_scan2<<<1, 512, 0, stream>>>(bsum, nb);
  k_scan3<<<nb, 256, 0, stream>>>(rp, bsum);
  k_scatter<<<(N_EDGES + 255) / 256, 256, 0, stream>>>(src, dst, edge_attr, rp, fill, cpair, cea);
  k_easum<<<nb, 256, 0, stream>>>(rp, cea, easum);

  for (int l = 0; l < LAYERS; ++l) {
    const float* hsrc = (l == 0) ? hEnc : hAgg;
    int mode = (l == 0) ? 0 : ((l == 3) ? 2 : 1);
    k_gemm_hp<<<(N_NODES + 127) / 128, 256, 0, stream>>>(
        hsrc, hEnc, ssAll + (l > 0 ? (l - 1) * 256 : 0), mode,
        W_lin + (size_t)l * DIM * DIM,
        att_src + l * HEADS * CHD, att_dst + l * HEADS * CHD, hp, a_s, a_d);
    k_attagg<<<(N_NODES + 3) / 4, 256, 0, stream>>>(
        hp, rp, cpair, cea, a_s, a_d, easum, small3, biasE,
        gat_bias + l * DIM, hAgg, l);
    k_bnstat<<<BN_BLK, 256, 0, stream>>>(hAgg, partial);
    k_bnfin<<<1, 128, 0, stream>>>(partial, bn_gamma + l * DIM, bn_beta + l * DIM,
                                   ssAll + l * 256);
  }

  const float* ss3 = ssAll + 3 * 256;
  k_gate<<<(N_NODES + 63) / 64, 256, 0, stream>>>(hAgg, ss3, gate_W1, gate_b1, gate_W2, gate_b2, gate);
  k_gptr<<<(N_GRAPH + 1 + 255) / 256, 256, 0, stream>>>(batch, gptr);
  k_pool<<<N_GRAPH, 128, 0, stream>>>(hAgg, ss3, gate, gptr, gr);
  k_mlp1<<<N_GRAPH / 8, 256, 0, stream>>>(gr, mlp_W1, mlp_b1, hid);
  k_mlp2<<<N_GRAPH / 8, 128, 0, stream>>>(hid, mlp_W2, mlp_b2, (float*)d_out);
}